// Round 1
// baseline (26756.491 us; speedup 1.0000x reference)
//
#include <hip/hip_runtime.h>
#include <hip/hip_bf16.h>
#include <math.h>

// Problem constants
#define B_    64
#define W_    255
#define S_    256
#define V_    16389
#define NLOC_ 16384
#define CLS_  16388
#define D_    512
#define H_    8
#define DH_   64
#define FF_   2048
#define L_    8
#define NTOK  (B_ * S_)   // 16384 tokens

// ---------------- embedding + positional encoding ----------------
// h[b,s,d] = emb[xc[b,s]][d] + PE(s,d); PE: ang = s / 10000^(2d/512),
// even d -> sin, odd d -> cos (computed in double; np-f32 ref tolerance is 3.75e-2)
__global__ __launch_bounds__(256) void embed_kernel(const int* __restrict__ x,
                                                    const float* __restrict__ emb,
                                                    float* __restrict__ h) {
  const int tok = blockIdx.x;
  const int bb = tok >> 8, ss = tok & 255;
  const int idx = (ss < W_) ? x[bb * W_ + ss] : CLS_;
  const float* e = emb + (size_t)idx * D_;
  float* hp = h + (size_t)tok * D_;
  #pragma unroll
  for (int r = 0; r < 2; ++r) {
    int d = threadIdx.x + r * 256;
    double den = pow(10000.0, (2.0 * (double)d) / 512.0);
    double ang = (double)ss / den;
    float pe = (d & 1) ? (float)cos(ang) : (float)sin(ang);
    hp[d] = e[d] + pe;
  }
}

// ---------------- LayerNorm (one block per token, D=512) ----------------
__global__ __launch_bounds__(256) void ln_kernel(const float* __restrict__ in,
                                                 float* __restrict__ out,
                                                 const float* __restrict__ sc,
                                                 const float* __restrict__ bi) {
  const int tok = blockIdx.x;
  const int tid = threadIdx.x;
  const float* xp = in + (size_t)tok * D_;
  float* yp = out + (size_t)tok * D_;
  float v0 = xp[tid], v1 = xp[tid + 256];
  float sum = v0 + v1;
  #pragma unroll
  for (int off = 32; off; off >>= 1) sum += __shfl_down(sum, off);
  __shared__ float red[4];
  __shared__ float stat[2];
  const int wave = tid >> 6, lane = tid & 63;
  if (lane == 0) red[wave] = sum;
  __syncthreads();
  if (tid == 0) stat[0] = (red[0] + red[1] + red[2] + red[3]) * (1.0f / D_);
  __syncthreads();
  const float mean = stat[0];
  float d0 = v0 - mean, d1 = v1 - mean;
  float ss = d0 * d0 + d1 * d1;
  #pragma unroll
  for (int off = 32; off; off >>= 1) ss += __shfl_down(ss, off);
  if (lane == 0) red[wave] = ss;
  __syncthreads();
  if (tid == 0) stat[1] = rsqrtf((red[0] + red[1] + red[2] + red[3]) * (1.0f / D_) + 1e-5f);
  __syncthreads();
  const float inv = stat[1];
  yp[tid] = d0 * inv * sc[tid] + bi[tid];
  yp[tid + 256] = d1 * inv * sc[tid + 256] + bi[tid + 256];
}

// ---------------- fp32 tiled GEMM: C[M,N] = A[M,K] @ W[K,N] (+bias, relu, residual) ----
// 64x64 tile per block, 16x16 threads each computing 4x4. BK=16.
template<bool BIAS, bool RELU, bool RES>
__global__ __launch_bounds__(256) void gemm_kernel(
    const float* __restrict__ A, int lda,
    const float* __restrict__ Bw, int ldb,
    const float* __restrict__ bias,
    const float* __restrict__ res,
    float* __restrict__ C, int ldc,
    int M, int N, int K) {
  __shared__ float As[16][64];   // As[k][row]
  __shared__ float Bs[16][64];   // Bs[k][col]
  const int tx = threadIdx.x, ty = threadIdx.y;
  const int tid = ty * 16 + tx;
  const int row0 = blockIdx.y * 64;
  const int col0 = blockIdx.x * 64;
  float acc[4][4] = {};
  const int ar = tid >> 2;        // 0..63 row within tile
  const int ak = (tid & 3) * 4;   // 0,4,8,12
  for (int k0 = 0; k0 < K; k0 += 16) {
    float4 av = *(const float4*)(A + (size_t)(row0 + ar) * lda + k0 + ak);
    As[ak + 0][ar] = av.x;
    As[ak + 1][ar] = av.y;
    As[ak + 2][ar] = av.z;
    As[ak + 3][ar] = av.w;
    #pragma unroll
    for (int i = 0; i < 4; ++i) {
      int idx = tid + i * 256;
      int bn = idx & 63, bk = idx >> 6;
      Bs[bk][bn] = Bw[(size_t)(k0 + bk) * ldb + col0 + bn];
    }
    __syncthreads();
    #pragma unroll
    for (int k = 0; k < 16; ++k) {
      float4 a4 = *(const float4*)(&As[k][ty * 4]);
      float4 b4 = *(const float4*)(&Bs[k][tx * 4]);
      float a[4] = {a4.x, a4.y, a4.z, a4.w};
      float b[4] = {b4.x, b4.y, b4.z, b4.w};
      #pragma unroll
      for (int i = 0; i < 4; ++i)
        #pragma unroll
        for (int j = 0; j < 4; ++j)
          acc[i][j] = fmaf(a[i], b[j], acc[i][j]);
    }
    __syncthreads();
  }
  #pragma unroll
  for (int i = 0; i < 4; ++i) {
    int row = row0 + ty * 4 + i;
    float* Cp = C + (size_t)row * ldc + col0 + tx * 4;
    #pragma unroll
    for (int j = 0; j < 4; ++j) {
      float v = acc[i][j];
      if (BIAS) v += bias[col0 + tx * 4 + j];
      if (RELU) v = fmaxf(v, 0.f);
      if (RES)  v += res[(size_t)row * ldc + col0 + tx * 4 + j];
      Cp[j] = v;
    }
  }
}

// ---------------- attention: one block per (b, h, q-row) ----------------
// qkv layout: [B,S,3D]; q at col 0, k at col D, v at col 2D; head hh uses cols hh*64..+64.
// o written in [B,S,D] layout (heads re-interleaved) to feed out-proj GEMM directly.
__global__ __launch_bounds__(256) void attn_kernel(const float* __restrict__ qkv,
                                                   float* __restrict__ o) {
  const int qr = blockIdx.x;   // 0..255
  const int hh = blockIdx.y;   // 0..7
  const int bb = blockIdx.z;   // 0..63
  const int tid = threadIdx.x; // 256
  __shared__ float qrow[DH_];
  __shared__ float sc[S_];
  __shared__ float red[4];
  __shared__ float oacc[4][DH_];
  const size_t base = (size_t)bb * S_ * (3 * D_);
  if (tid < DH_) qrow[tid] = qkv[base + (size_t)qr * (3 * D_) + hh * DH_ + tid];
  __syncthreads();
  {
    const float* kp = qkv + base + (size_t)tid * (3 * D_) + D_ + hh * DH_;
    float s = 0.f;
    #pragma unroll
    for (int d = 0; d < DH_; ++d) s = fmaf(qrow[d], kp[d], s);
    sc[tid] = s * 0.125f;   // 1/sqrt(64)
  }
  __syncthreads();
  float v = sc[tid];
  float m = v;
  #pragma unroll
  for (int off = 32; off; off >>= 1) m = fmaxf(m, __shfl_down(m, off));
  const int wave = tid >> 6, lane = tid & 63;
  if (lane == 0) red[wave] = m;
  __syncthreads();
  float gmax = fmaxf(fmaxf(red[0], red[1]), fmaxf(red[2], red[3]));
  __syncthreads();
  float e = expf(v - gmax);
  float s2 = e;
  #pragma unroll
  for (int off = 32; off; off >>= 1) s2 += __shfl_down(s2, off);
  if (lane == 0) red[wave] = s2;
  __syncthreads();
  float gsum = red[0] + red[1] + red[2] + red[3];
  sc[tid] = e / gsum;
  __syncthreads();
  {
    const int d = tid & 63, jb = tid >> 6;
    const float* vp = qkv + base + 2 * D_ + hh * DH_ + d;
    float acc = 0.f;
    for (int j = jb * 64; j < jb * 64 + 64; ++j)
      acc = fmaf(sc[j], vp[(size_t)j * (3 * D_)], acc);
    oacc[jb][d] = acc;
  }
  __syncthreads();
  if (tid < DH_) {
    float r = oacc[0][tid] + oacc[1][tid] + oacc[2][tid] + oacc[3][tid];
    o[((size_t)bb * S_ + qr) * D_ + hh * DH_ + tid] = r;
  }
}

extern "C" void kernel_launch(void* const* d_in, const int* in_sizes, int n_in,
                              void* d_out, int out_size, void* d_ws, size_t ws_size,
                              hipStream_t stream) {
  const int*   x      = (const int*)  d_in[0];
  const float* emb    = (const float*)d_in[1];
  const float* qkv_w  = (const float*)d_in[2];
  const float* qkv_b  = (const float*)d_in[3];
  const float* out_w  = (const float*)d_in[4];
  const float* out_b  = (const float*)d_in[5];
  const float* ln1_s  = (const float*)d_in[6];
  const float* ln1_b  = (const float*)d_in[7];
  const float* ln2_s  = (const float*)d_in[8];
  const float* ln2_b  = (const float*)d_in[9];
  const float* ff1_w  = (const float*)d_in[10];
  const float* ff1_b  = (const float*)d_in[11];
  const float* ff2_w  = (const float*)d_in[12];
  const float* ff2_b  = (const float*)d_in[13];
  const float* fn_s   = (const float*)d_in[14];
  const float* fn_b   = (const float*)d_in[15];
  const float* head_w = (const float*)d_in[16];
  float* out = (float*)d_out;

  // workspace layout (floats): h[NTOK*D] | x2[NTOK*D] | big[NTOK*FF]
  // big holds qkv [NTOK*3D] during attention, with obuf aliased in its tail
  // (3D + D = FF, exact fit); later big holds ff_mid [NTOK*FF].  ~192 MiB total.
  float* h    = (float*)d_ws;
  float* x2   = h  + (size_t)NTOK * D_;
  float* big  = x2 + (size_t)NTOK * D_;
  float* obuf = big + (size_t)NTOK * (3 * D_);

  embed_kernel<<<NTOK, 256, 0, stream>>>(x, emb, h);
  for (int l = 0; l < L_; ++l) {
    ln_kernel<<<NTOK, 256, 0, stream>>>(h, x2, ln1_s + l * D_, ln1_b + l * D_);
    gemm_kernel<true, false, false><<<dim3(3 * D_ / 64, NTOK / 64), dim3(16, 16), 0, stream>>>(
        x2, D_, qkv_w + (size_t)l * D_ * 3 * D_, 3 * D_, qkv_b + (size_t)l * 3 * D_,
        nullptr, big, 3 * D_, NTOK, 3 * D_, D_);
    attn_kernel<<<dim3(S_, H_, B_), 256, 0, stream>>>(big, obuf);
    gemm_kernel<true, false, true><<<dim3(D_ / 64, NTOK / 64), dim3(16, 16), 0, stream>>>(
        obuf, D_, out_w + (size_t)l * D_ * D_, D_, out_b + (size_t)l * D_,
        h, h, D_, NTOK, D_, D_);
    ln_kernel<<<NTOK, 256, 0, stream>>>(h, x2, ln2_s + l * D_, ln2_b + l * D_);
    gemm_kernel<true, true, false><<<dim3(FF_ / 64, NTOK / 64), dim3(16, 16), 0, stream>>>(
        x2, D_, ff1_w + (size_t)l * D_ * FF_, FF_, ff1_b + (size_t)l * FF_,
        nullptr, big, FF_, NTOK, FF_, D_);
    gemm_kernel<true, false, true><<<dim3(D_ / 64, NTOK / 64), dim3(16, 16), 0, stream>>>(
        big, FF_, ff2_w + (size_t)l * FF_ * D_, D_, ff2_b + (size_t)l * D_,
        h, h, D_, NTOK, D_, FF_);
  }
  ln_kernel<<<NTOK, 256, 0, stream>>>(h, x2, fn_s, fn_b);
  // head: only last token of each batch row; A row stride = S*D, W row stride = V
  gemm_kernel<false, false, false><<<dim3(NLOC_ / 64, 1), dim3(16, 16), 0, stream>>>(
      x2 + (size_t)(S_ - 1) * D_, S_ * D_, head_w, V_, nullptr,
      nullptr, out, NLOC_, B_, NLOC_, D_);
}

// Round 2
// 2949.817 us; speedup vs baseline: 9.0706x; 9.0706x over previous
//
#include <hip/hip_runtime.h>
#include <hip/hip_bf16.h>
#include <math.h>

#define B_    64
#define W_    255
#define S_    256
#define V_    16389
#define NLOC_ 16384
#define CLS_  16388
#define D_    512
#define H_    8
#define DH_   64
#define FF_   2048
#define L_    8
#define NTOK  (B_ * S_)

typedef __attribute__((ext_vector_type(4))) float f32x4;
typedef __attribute__((ext_vector_type(8))) short s16x8;

__device__ inline unsigned short f2b(float f) {
  union { float f; unsigned u; } v; v.f = f;
  unsigned r = v.u + 0x7fff + ((v.u >> 16) & 1);
  return (unsigned short)(r >> 16);
}
__device__ inline float b2f(unsigned short b) {
  union { unsigned u; float f; } v; v.u = ((unsigned)b) << 16;
  return v.f;
}
__device__ inline void gl_lds16(const void* g, void* l) {
  __builtin_amdgcn_global_load_lds((const __attribute__((address_space(1))) unsigned int*)g,
                                   (__attribute__((address_space(3))) unsigned int*)l, 16, 0, 0);
}

// ---------------- embedding + positional encoding (fp32 fast path) ----------------
__global__ __launch_bounds__(256) void embed_kernel(const int* __restrict__ x,
                                                    const float* __restrict__ emb,
                                                    float* __restrict__ h) {
  const int tok = blockIdx.x;
  const int bb = tok >> 8, ss = tok & 255;
  const int idx = (ss < W_) ? x[bb * W_ + ss] : CLS_;
  const float* e = emb + (size_t)idx * D_;
  float* hp = h + (size_t)tok * D_;
  #pragma unroll
  for (int r = 0; r < 2; ++r) {
    int d = threadIdx.x + r * 256;
    // 1/10000^(2d/512) = 2^(-d * log2(1e4)/256)
    float ex = exp2f(-(float)d * (13.287712379549449f / 256.0f));
    float ang = (float)ss * ex;
    float pe = (d & 1) ? cosf(ang) : sinf(ang);
    hp[d] = e[d] + pe;
  }
}

// ---------------- LayerNorm (fp32 in, bf16 out), one block per token ----------------
__global__ __launch_bounds__(256) void ln_kernel(const float* __restrict__ in,
                                                 unsigned short* __restrict__ out,
                                                 const float* __restrict__ sc,
                                                 const float* __restrict__ bi) {
  const int tok = blockIdx.x;
  const int tid = threadIdx.x;
  const float* xp = in + (size_t)tok * D_;
  unsigned short* yp = out + (size_t)tok * D_;
  float v0 = xp[tid], v1 = xp[tid + 256];
  float sum = v0 + v1;
  #pragma unroll
  for (int off = 32; off; off >>= 1) sum += __shfl_down(sum, off);
  __shared__ float red[4];
  __shared__ float stat[2];
  const int wave = tid >> 6, lane = tid & 63;
  if (lane == 0) red[wave] = sum;
  __syncthreads();
  if (tid == 0) stat[0] = (red[0] + red[1] + red[2] + red[3]) * (1.0f / D_);
  __syncthreads();
  const float mean = stat[0];
  float d0 = v0 - mean, d1 = v1 - mean;
  float ss = d0 * d0 + d1 * d1;
  #pragma unroll
  for (int off = 32; off; off >>= 1) ss += __shfl_down(ss, off);
  if (lane == 0) red[wave] = ss;
  __syncthreads();
  if (tid == 0) stat[1] = rsqrtf((red[0] + red[1] + red[2] + red[3]) * (1.0f / D_) + 1e-5f);
  __syncthreads();
  const float inv = stat[1];
  yp[tid]       = f2b(d0 * inv * sc[tid] + bi[tid]);
  yp[tid + 256] = f2b(d1 * inv * sc[tid + 256] + bi[tid + 256]);
}

// ---------------- weight transpose + fp32->bf16: W[K,N] (row stride ldn) -> Wt[N,K] ----
__global__ __launch_bounds__(256) void wconv_kernel(const float* __restrict__ W,
                                                    unsigned short* __restrict__ Wt,
                                                    int K, int ldn) {
  __shared__ float t[64][65];
  const int n0 = blockIdx.x * 64, k0 = blockIdx.y * 64;
  const int r = threadIdx.x >> 6;      // 0..3
  const int c = threadIdx.x & 63;      // 0..63
  #pragma unroll
  for (int i = 0; i < 16; ++i) {
    int kk = i * 4 + r;
    t[kk][c] = W[(size_t)(k0 + kk) * ldn + n0 + c];
  }
  __syncthreads();
  #pragma unroll
  for (int i = 0; i < 16; ++i) {
    int nn = i * 4 + r;
    Wt[(size_t)(n0 + nn) * K + k0 + c] = f2b(t[c][nn]);
  }
}

// ---------------- MFMA GEMM: C[M,N] = A[M,K](bf16) @ Wt[N,K]^T(bf16) + epilogue ------
// 128x128 tile, BK=32, 4 waves (2x2), each wave 4x4 frags of 16x16x32.
template<bool BIAS, bool RELU, bool RES, bool OUTBF>
__global__ __launch_bounds__(256) void mfma_gemm(
    const unsigned short* __restrict__ A, long lda,
    const unsigned short* __restrict__ Bt,
    const float* __restrict__ bias,
    float* __restrict__ Cres,
    unsigned short* __restrict__ Cbf,
    int M, int N, int K, int ldc) {
  __shared__ unsigned short As[128 * 32];
  __shared__ unsigned short Bs[128 * 32];
  const int tid = threadIdx.x;
  const int w = tid >> 6, lane = tid & 63;
  const int wm = w >> 1, wn = w & 1;
  const int row0 = blockIdx.y * 128, col0 = blockIdx.x * 128;
  f32x4 acc[4][4] = {};
  const int sr = lane >> 2;        // row within 16-row segment
  const int sc = (lane & 3) * 8;   // 8-elem chunk
  const int fr = lane & 15, fo = (lane >> 4) * 8;
  for (int k0 = 0; k0 < K; k0 += 32) {
    #pragma unroll
    for (int i = 0; i < 2; ++i) {
      int seg = w * 2 + i;
      int r = seg * 16 + sr;
      int ar = row0 + r; if (ar >= M) ar = M - 1;
      gl_lds16(A + (size_t)ar * lda + k0 + sc, &As[seg * 512]);
      gl_lds16(Bt + (size_t)(col0 + r) * K + k0 + sc, &Bs[seg * 512]);
    }
    __syncthreads();
    s16x8 af[4], bf[4];
    #pragma unroll
    for (int mi = 0; mi < 4; ++mi)
      af[mi] = *(const s16x8*)&As[(wm * 64 + mi * 16 + fr) * 32 + fo];
    #pragma unroll
    for (int ni = 0; ni < 4; ++ni)
      bf[ni] = *(const s16x8*)&Bs[(wn * 64 + ni * 16 + fr) * 32 + fo];
    #pragma unroll
    for (int mi = 0; mi < 4; ++mi)
      #pragma unroll
      for (int ni = 0; ni < 4; ++ni)
        acc[mi][ni] = __builtin_amdgcn_mfma_f32_16x16x32_bf16(af[mi], bf[ni], acc[mi][ni], 0, 0, 0);
    __syncthreads();
  }
  const int er = (lane >> 4) * 4;
  const int ec = lane & 15;
  #pragma unroll
  for (int ni = 0; ni < 4; ++ni) {
    int col = col0 + wn * 64 + ni * 16 + ec;
    float bv = BIAS ? bias[col] : 0.0f;
    #pragma unroll
    for (int mi = 0; mi < 4; ++mi) {
      int rowb = row0 + wm * 64 + mi * 16 + er;
      #pragma unroll
      for (int r = 0; r < 4; ++r) {
        int row = rowb + r;
        if (row < M) {
          float v = acc[mi][ni][r] + bv;
          if (RELU) v = fmaxf(v, 0.0f);
          size_t idx = (size_t)row * ldc + col;
          if (OUTBF) Cbf[idx] = f2b(v);
          else if (RES) Cres[idx] = Cres[idx] + v;
          else Cres[idx] = v;
        }
      }
    }
  }
}

// ---------------- V transpose: qkvb V-cols -> vtg[(b*H+h)][d][j] (bf16) ----------------
__global__ __launch_bounds__(256) void vt_kernel(const unsigned short* __restrict__ qkvb,
                                                 unsigned short* __restrict__ vtg) {
  const int bh = blockIdx.x;     // b*8+h
  const int jt = blockIdx.y;     // j tile of 64
  const int bb = bh >> 3, hh = bh & 7;
  __shared__ unsigned short t[64][72];   // [j_local][d], padded row stride 144B (16B-aligned)
  const int r = threadIdx.x >> 2;        // 0..63
  const int c = (threadIdx.x & 3) * 16;  // 0,16,32,48
  const unsigned short* src = qkvb + (size_t)(bb * 256 + jt * 64 + r) * 1536 + 1024 + hh * 64 + c;
  *(s16x8*)&t[r][c]     = *(const s16x8*)src;
  *(s16x8*)&t[r][c + 8] = *(const s16x8*)(src + 8);
  __syncthreads();
  // write: thread handles d=r, j-chunk c..c+15
  unsigned short tmp[16];
  #pragma unroll
  for (int i = 0; i < 16; ++i) tmp[i] = t[c + i][r];
  unsigned short* dst = vtg + ((size_t)bh * 64 + r) * 256 + jt * 64 + c;
  *(s16x8*)dst       = *(const s16x8*)&tmp[0];
  *(s16x8*)(dst + 8) = *(const s16x8*)&tmp[8];
}

// ---------------- fused MFMA attention: one block per (b,h) ----------------
__global__ __launch_bounds__(256) void attn_mfma(const unsigned short* __restrict__ qkvb,
                                                 const unsigned short* __restrict__ vtg,
                                                 unsigned short* __restrict__ obuf) {
  const int bh = blockIdx.x;
  const int bb = bh >> 3, hh = bh & 7;
  const int tid = threadIdx.x, w = tid >> 6, lane = tid & 63;
  __shared__ unsigned short Pl[4][16][264];   // per-wave P strip, padded (528B rows, 16B-aligned)
  const int fr = lane & 15, fg = lane >> 4;
  const unsigned short* qbase = qkvb + (size_t)bb * 256 * 1536 + hh * 64;
  const unsigned short* kbase = qbase + 512;
  const unsigned short* vb = vtg + (size_t)bh * 64 * 256;
  unsigned short* ob = obuf + (size_t)bb * 256 * 512 + hh * 64;

  for (int s = w; s < 16; s += 4) {
    const int q0 = s * 16;
    // ---- S = Q K^T (strip: 16 q x 256 keys) ----
    f32x4 sacc[16] = {};
    s16x8 aq[2];
    #pragma unroll
    for (int kk = 0; kk < 2; ++kk)
      aq[kk] = *(const s16x8*)(qbase + (size_t)(q0 + fr) * 1536 + kk * 32 + fg * 8);
    #pragma unroll
    for (int ni = 0; ni < 16; ++ni) {
      #pragma unroll
      for (int kk = 0; kk < 2; ++kk) {
        s16x8 bk = *(const s16x8*)(kbase + (size_t)(ni * 16 + fr) * 1536 + kk * 32 + fg * 8);
        sacc[ni] = __builtin_amdgcn_mfma_f32_16x16x32_bf16(aq[kk], bk, sacc[ni], 0, 0, 0);
      }
    }
    // ---- softmax over keys, per row (rows live in 16-lane groups) ----
    #pragma unroll
    for (int rr = 0; rr < 4; ++rr) {
      float mx = -1e30f;
      #pragma unroll
      for (int ni = 0; ni < 16; ++ni) mx = fmaxf(mx, sacc[ni][rr]);
      #pragma unroll
      for (int off = 1; off <= 8; off <<= 1) mx = fmaxf(mx, __shfl_xor(mx, off));
      float sum = 0.0f;
      #pragma unroll
      for (int ni = 0; ni < 16; ++ni) {
        float e = __expf((sacc[ni][rr] - mx) * 0.125f);
        sacc[ni][rr] = e; sum += e;
      }
      #pragma unroll
      for (int off = 1; off <= 8; off <<= 1) sum += __shfl_xor(sum, off);
      float inv = 1.0f / sum;
      #pragma unroll
      for (int ni = 0; ni < 16; ++ni) sacc[ni][rr] *= inv;
    }
    // ---- P: C-layout -> A-layout via per-wave LDS ----
    #pragma unroll
    for (int ni = 0; ni < 16; ++ni)
      #pragma unroll
      for (int rr = 0; rr < 4; ++rr)
        Pl[w][fg * 4 + rr][ni * 16 + fr] = f2b(sacc[ni][rr]);
    // ---- O = P V (16 x 64), B-frags from L1-resident V^T ----
    f32x4 oacc[4] = {};
    #pragma unroll
    for (int kk = 0; kk < 8; ++kk) {
      s16x8 ap = *(const s16x8*)&Pl[w][fr][kk * 32 + fg * 8];
      #pragma unroll
      for (int ni = 0; ni < 4; ++ni) {
        s16x8 bv = *(const s16x8*)(vb + (size_t)(ni * 16 + fr) * 256 + kk * 32 + fg * 8);
        oacc[ni] = __builtin_amdgcn_mfma_f32_16x16x32_bf16(ap, bv, oacc[ni], 0, 0, 0);
      }
    }
    #pragma unroll
    for (int ni = 0; ni < 4; ++ni)
      #pragma unroll
      for (int rr = 0; rr < 4; ++rr)
        ob[(size_t)(q0 + fg * 4 + rr) * 512 + ni * 16 + fr] = f2b(oacc[ni][rr]);
  }
}

extern "C" void kernel_launch(void* const* d_in, const int* in_sizes, int n_in,
                              void* d_out, int out_size, void* d_ws, size_t ws_size,
                              hipStream_t stream) {
  const int*   x      = (const int*)  d_in[0];
  const float* emb    = (const float*)d_in[1];
  const float* qkv_w  = (const float*)d_in[2];
  const float* qkv_b  = (const float*)d_in[3];
  const float* out_w  = (const float*)d_in[4];
  const float* out_b  = (const float*)d_in[5];
  const float* ln1_s  = (const float*)d_in[6];
  const float* ln1_b  = (const float*)d_in[7];
  const float* ln2_s  = (const float*)d_in[8];
  const float* ln2_b  = (const float*)d_in[9];
  const float* ff1_w  = (const float*)d_in[10];
  const float* ff1_b  = (const float*)d_in[11];
  const float* ff2_w  = (const float*)d_in[12];
  const float* ff2_b  = (const float*)d_in[13];
  const float* fn_s   = (const float*)d_in[14];
  const float* fn_b   = (const float*)d_in[15];
  const float* head_w = (const float*)d_in[16];
  float* out = (float*)d_out;

  // workspace layout (bytes):
  // h f32 32MB | x2b bf16 16MB | qkvb bf16 48MB | vtg bf16 16.8MB | obuf bf16 16MB |
  // wt(4 per-layer) 6.3MB | wth 16.8MB.  ffmid (64MB bf16) aliases qkvb+vtg+obuf (dead then).
  char* p = (char*)d_ws;
  float* h = (float*)p;                      p += (size_t)NTOK * D_ * 4;
  unsigned short* x2b = (unsigned short*)p;  p += (size_t)NTOK * D_ * 2;
  unsigned short* qkvb = (unsigned short*)p; p += (size_t)NTOK * 3 * D_ * 2;
  unsigned short* vtg = (unsigned short*)p;  p += (size_t)B_ * H_ * DH_ * S_ * 2;
  unsigned short* obuf = (unsigned short*)p; p += (size_t)NTOK * D_ * 2;
  unsigned short* wt_qkv = (unsigned short*)p; p += (size_t)D_ * 3 * D_ * 2;
  unsigned short* wt_out = (unsigned short*)p; p += (size_t)D_ * D_ * 2;
  unsigned short* wt_ff1 = (unsigned short*)p; p += (size_t)D_ * FF_ * 2;
  unsigned short* wt_ff2 = (unsigned short*)p; p += (size_t)FF_ * D_ * 2;
  unsigned short* wth = (unsigned short*)p;    p += (size_t)NLOC_ * D_ * 2;
  unsigned short* ffmid = qkvb;  // alias: qkvb(48)+vtg(16.8)+obuf(16) >= 64MB

  embed_kernel<<<NTOK, 256, 0, stream>>>(x, emb, h);
  // head weight: W[512,16389] -> wth[16384,512] (first 16384 cols)
  wconv_kernel<<<dim3(NLOC_ / 64, D_ / 64), 256, 0, stream>>>(head_w, wth, D_, V_);

  for (int l = 0; l < L_; ++l) {
    wconv_kernel<<<dim3(3 * D_ / 64, D_ / 64), 256, 0, stream>>>(
        qkv_w + (size_t)l * D_ * 3 * D_, wt_qkv, D_, 3 * D_);
    wconv_kernel<<<dim3(D_ / 64, D_ / 64), 256, 0, stream>>>(
        out_w + (size_t)l * D_ * D_, wt_out, D_, D_);
    wconv_kernel<<<dim3(FF_ / 64, D_ / 64), 256, 0, stream>>>(
        ff1_w + (size_t)l * D_ * FF_, wt_ff1, D_, FF_);
    wconv_kernel<<<dim3(D_ / 64, FF_ / 64), 256, 0, stream>>>(
        ff2_w + (size_t)l * FF_ * D_, wt_ff2, FF_, D_);

    ln_kernel<<<NTOK, 256, 0, stream>>>(h, x2b, ln1_s + l * D_, ln1_b + l * D_);
    mfma_gemm<true, false, false, true><<<dim3(3 * D_ / 128, NTOK / 128), 256, 0, stream>>>(
        x2b, D_, wt_qkv, qkv_b + (size_t)l * 3 * D_, nullptr, qkvb,
        NTOK, 3 * D_, D_, 3 * D_);
    vt_kernel<<<dim3(B_ * H_, 4), 256, 0, stream>>>(qkvb, vtg);
    attn_mfma<<<B_ * H_, 256, 0, stream>>>(qkvb, vtg, obuf);
    mfma_gemm<true, false, true, false><<<dim3(D_ / 128, NTOK / 128), 256, 0, stream>>>(
        obuf, D_, wt_out, out_b + (size_t)l * D_, h, nullptr,
        NTOK, D_, D_, D_);
    ln_kernel<<<NTOK, 256, 0, stream>>>(h, x2b, ln2_s + l * D_, ln2_b + l * D_);
    mfma_gemm<true, true, false, true><<<dim3(FF_ / 128, NTOK / 128), 256, 0, stream>>>(
        x2b, D_, wt_ff1, ff1_b + (size_t)l * FF_, nullptr, ffmid,
        NTOK, FF_, D_, FF_);
    mfma_gemm<true, false, true, false><<<dim3(D_ / 128, NTOK / 128), 256, 0, stream>>>(
        ffmid, FF_, wt_ff2, ff2_b + (size_t)l * D_, h, nullptr,
        NTOK, D_, FF_, D_);
  }
  ln_kernel<<<NTOK, 256, 0, stream>>>(h, x2b, fn_s, fn_b);
  // head: A = last-token rows of x2b (row stride S*D), M=64 (clamped loads, guarded stores)
  mfma_gemm<false, false, false, false><<<dim3(NLOC_ / 128, 1), 256, 0, stream>>>(
      x2b + (size_t)(S_ - 1) * D_, (long)S_ * D_, wth, nullptr, out, nullptr,
      B_, NLOC_, D_, NLOC_);
}

// Round 3
// 2640.899 us; speedup vs baseline: 10.1316x; 1.1170x over previous
//
#include <hip/hip_runtime.h>
#include <hip/hip_bf16.h>
#include <math.h>

#define B_    64
#define W_    255
#define S_    256
#define V_    16389
#define NLOC_ 16384
#define CLS_  16388
#define D_    512
#define H_    8
#define DH_   64
#define FF_   2048
#define L_    8
#define NTOK  (B_ * S_)

typedef __attribute__((ext_vector_type(4))) float f32x4;
typedef __attribute__((ext_vector_type(8))) short s16x8;

__device__ inline unsigned short f2b(float f) {
  union { float f; unsigned u; } v; v.f = f;
  unsigned r = v.u + 0x7fff + ((v.u >> 16) & 1);
  return (unsigned short)(r >> 16);
}
__device__ inline void gl_lds16(const void* g, void* l) {
  __builtin_amdgcn_global_load_lds((const __attribute__((address_space(1))) unsigned int*)g,
                                   (__attribute__((address_space(3))) unsigned int*)l, 16, 0, 0);
}

// ---------------- embedding + positional encoding ----------------
__global__ __launch_bounds__(256) void embed_kernel(const int* __restrict__ x,
                                                    const float* __restrict__ emb,
                                                    float* __restrict__ h) {
  const int tok = blockIdx.x;
  const int bb = tok >> 8, ss = tok & 255;
  const int idx = (ss < W_) ? x[bb * W_ + ss] : CLS_;
  const float* e = emb + (size_t)idx * D_;
  float* hp = h + (size_t)tok * D_;
  #pragma unroll
  for (int r = 0; r < 2; ++r) {
    int d = threadIdx.x + r * 256;
    float ex = exp2f(-(float)d * (13.287712379549449f / 256.0f));
    float ang = (float)ss * ex;
    float pe = (d & 1) ? cosf(ang) : sinf(ang);
    hp[d] = e[d] + pe;
  }
}

// ---------------- LayerNorm (fp32 in, bf16 out) ----------------
__global__ __launch_bounds__(256) void ln_kernel(const float* __restrict__ in,
                                                 unsigned short* __restrict__ out,
                                                 const float* __restrict__ sc,
                                                 const float* __restrict__ bi) {
  const int tok = blockIdx.x;
  const int tid = threadIdx.x;
  const float* xp = in + (size_t)tok * D_;
  unsigned short* yp = out + (size_t)tok * D_;
  float v0 = xp[tid], v1 = xp[tid + 256];
  float sum = v0 + v1;
  #pragma unroll
  for (int off = 32; off; off >>= 1) sum += __shfl_down(sum, off);
  __shared__ float red[4];
  __shared__ float stat[2];
  const int wave = tid >> 6, lane = tid & 63;
  if (lane == 0) red[wave] = sum;
  __syncthreads();
  if (tid == 0) stat[0] = (red[0] + red[1] + red[2] + red[3]) * (1.0f / D_);
  __syncthreads();
  const float mean = stat[0];
  float d0 = v0 - mean, d1 = v1 - mean;
  float ss = d0 * d0 + d1 * d1;
  #pragma unroll
  for (int off = 32; off; off >>= 1) ss += __shfl_down(ss, off);
  if (lane == 0) red[wave] = ss;
  __syncthreads();
  if (tid == 0) stat[1] = rsqrtf((red[0] + red[1] + red[2] + red[3]) * (1.0f / D_) + 1e-5f);
  __syncthreads();
  const float inv = stat[1];
  yp[tid]       = f2b(d0 * inv * sc[tid] + bi[tid]);
  yp[tid + 256] = f2b(d1 * inv * sc[tid + 256] + bi[tid + 256]);
}

// ---------------- weight transpose + fp32->bf16: W[K,N] -> Wt[N,K] ----------------
__global__ __launch_bounds__(256) void wconv_kernel(const float* __restrict__ W,
                                                    unsigned short* __restrict__ Wt,
                                                    int K, int ldn) {
  __shared__ float t[64][65];
  const int n0 = blockIdx.x * 64, k0 = blockIdx.y * 64;
  const int r = threadIdx.x >> 6;
  const int c = threadIdx.x & 63;
  #pragma unroll
  for (int i = 0; i < 16; ++i) {
    int kk = i * 4 + r;
    t[kk][c] = W[(size_t)(k0 + kk) * ldn + n0 + c];
  }
  __syncthreads();
  #pragma unroll
  for (int i = 0; i < 16; ++i) {
    int nn = i * 4 + r;
    Wt[(size_t)(n0 + nn) * K + k0 + c] = f2b(t[c][nn]);
  }
}

// ---------------- MFMA GEMM: C[M,N] = A[M,K](bf16) @ Wt[N,K]^T(bf16) + epilogue ------
// 128x128 tile, BK=32, 4 waves (2x2), each wave 4x4 frags of 16x16x32.
// XOR-swizzled LDS (chunk ^= (row>>1)&3) for conflict-free ds_read_b128.
// Epilogue staged through LDS for coalesced 16B global stores.
template<bool BIAS, bool RELU, bool RES, bool OUTBF>
__global__ __launch_bounds__(256) void mfma_gemm(
    const unsigned short* __restrict__ A, long lda,
    const unsigned short* __restrict__ Bt,
    const float* __restrict__ bias,
    float* __restrict__ Cres,
    unsigned short* __restrict__ Cbf,
    int M, int N, int K, int ldc) {
  __shared__ __align__(16) unsigned char smem[16384];
  unsigned short* As = (unsigned short*)smem;   // 128 x 32 bf16
  unsigned short* Bs = As + 128 * 32;           // 128 x 32 bf16
  const int tid = threadIdx.x;
  const int w = tid >> 6, lane = tid & 63;
  const int wm = w >> 1, wn = w & 1;
  const int row0 = blockIdx.y * 128, col0 = blockIdx.x * 128;
  f32x4 acc[4][4] = {};
  const int sr = lane >> 2;                              // staging row within seg
  const int sq = ((lane & 3) ^ ((sr >> 1) & 3)) * 8;     // swizzled global chunk (elems)
  const int fr = lane & 15;
  const int fg = lane >> 4;
  const int fo = (fg ^ ((fr >> 1) & 3)) * 8;             // swizzled LDS chunk (elems)
  for (int k0 = 0; k0 < K; k0 += 32) {
    #pragma unroll
    for (int i = 0; i < 2; ++i) {
      int seg = w * 2 + i;
      int r = seg * 16 + sr;
      int ar = row0 + r; if (ar >= M) ar = M - 1;
      gl_lds16(A + (size_t)ar * lda + k0 + sq, As + seg * 512);
      gl_lds16(Bt + (size_t)(col0 + r) * K + k0 + sq, Bs + seg * 512);
    }
    __syncthreads();
    s16x8 af[4], bf[4];
    #pragma unroll
    for (int mi = 0; mi < 4; ++mi)
      af[mi] = *(const s16x8*)&As[(wm * 64 + mi * 16 + fr) * 32 + fo];
    #pragma unroll
    for (int ni = 0; ni < 4; ++ni)
      bf[ni] = *(const s16x8*)&Bs[(wn * 64 + ni * 16 + fr) * 32 + fo];
    #pragma unroll
    for (int mi = 0; mi < 4; ++mi)
      #pragma unroll
      for (int ni = 0; ni < 4; ++ni)
        acc[mi][ni] = __builtin_amdgcn_mfma_f32_16x16x32_bf16(af[mi], bf[ni], acc[mi][ni], 0, 0, 0);
    __syncthreads();
  }
  const int er4 = fg * 4;   // frag row offset within 16-row block
  const int ec = fr;        // frag col
  if (OUTBF) {
    unsigned short* Cs = (unsigned short*)smem;   // 64 x 128 bf16 (16 KB)
    #pragma unroll
    for (int half = 0; half < 2; ++half) {
      __syncthreads();
      if (wm == half) {
        #pragma unroll
        for (int mi = 0; mi < 4; ++mi)
          #pragma unroll
          for (int ni = 0; ni < 4; ++ni) {
            int col = wn * 64 + ni * 16 + ec;
            float bv = BIAS ? bias[col0 + col] : 0.0f;
            #pragma unroll
            for (int r = 0; r < 4; ++r) {
              float v = acc[mi][ni][r] + bv;
              if (RELU) v = fmaxf(v, 0.0f);
              Cs[(mi * 16 + er4 + r) * 128 + col] = f2b(v);
            }
          }
      }
      __syncthreads();
      #pragma unroll
      for (int i = 0; i < 4; ++i) {
        int chunk = i * 256 + tid;
        int row = chunk >> 4, cc = chunk & 15;
        int grow = row0 + half * 64 + row;
        if (grow < M)
          *(s16x8*)(Cbf + (size_t)grow * ldc + col0 + cc * 8) =
              *(const s16x8*)&Cs[row * 128 + cc * 8];
      }
    }
  } else {
    float* Csf = (float*)smem;   // 32 x 128 f32 (16 KB)
    #pragma unroll
    for (int q = 0; q < 4; ++q) {
      __syncthreads();
      if (wm == (q >> 1)) {
        #pragma unroll
        for (int m2 = 0; m2 < 2; ++m2) {
          int mi = (q & 1) * 2 + m2;
          #pragma unroll
          for (int ni = 0; ni < 4; ++ni) {
            int col = wn * 64 + ni * 16 + ec;
            float bv = BIAS ? bias[col0 + col] : 0.0f;
            #pragma unroll
            for (int r = 0; r < 4; ++r) {
              float v = acc[mi][ni][r] + bv;
              if (RELU) v = fmaxf(v, 0.0f);
              Csf[(m2 * 16 + er4 + r) * 128 + col] = v;
            }
          }
        }
      }
      __syncthreads();
      #pragma unroll
      for (int i = 0; i < 4; ++i) {
        int chunk = i * 256 + tid;
        int row = chunk >> 5, cc = chunk & 31;
        int grow = row0 + q * 32 + row;
        if (grow < M) {
          float4 v = *(const float4*)&Csf[row * 128 + cc * 4];
          float* gp = Cres + (size_t)grow * ldc + col0 + cc * 4;
          if (RES) {
            float4 hv = *(const float4*)gp;
            v.x += hv.x; v.y += hv.y; v.z += hv.z; v.w += hv.w;
          }
          *(float4*)gp = v;
        }
      }
    }
  }
}

// ---------------- V transpose: qkvb V-cols -> vtg[(b*H+h)][d][j] (bf16) ----------------
__global__ __launch_bounds__(256) void vt_kernel(const unsigned short* __restrict__ qkvb,
                                                 unsigned short* __restrict__ vtg) {
  const int bh = blockIdx.x;
  const int jt = blockIdx.y;
  const int bb = bh >> 3, hh = bh & 7;
  __shared__ unsigned short t[64][72];
  const int r = threadIdx.x >> 2;
  const int c = (threadIdx.x & 3) * 16;
  const unsigned short* src = qkvb + (size_t)(bb * 256 + jt * 64 + r) * 1536 + 1024 + hh * 64 + c;
  *(s16x8*)&t[r][c]     = *(const s16x8*)src;
  *(s16x8*)&t[r][c + 8] = *(const s16x8*)(src + 8);
  __syncthreads();
  unsigned short tmp[16];
  #pragma unroll
  for (int i = 0; i < 16; ++i) tmp[i] = t[c + i][r];
  unsigned short* dst = vtg + ((size_t)bh * 64 + r) * 256 + jt * 64 + c;
  *(s16x8*)dst       = *(const s16x8*)&tmp[0];
  *(s16x8*)(dst + 8) = *(const s16x8*)&tmp[8];
}

// ---------------- fused MFMA attention: one block per (b,h) ----------------
__global__ __launch_bounds__(256) void attn_mfma(const unsigned short* __restrict__ qkvb,
                                                 const unsigned short* __restrict__ vtg,
                                                 unsigned short* __restrict__ obuf) {
  const int bh = blockIdx.x;
  const int bb = bh >> 3, hh = bh & 7;
  const int tid = threadIdx.x, w = tid >> 6, lane = tid & 63;
  __shared__ unsigned short Pl[4][16][264];
  const int fr = lane & 15, fg = lane >> 4;
  const unsigned short* qbase = qkvb + (size_t)bb * 256 * 1536 + hh * 64;
  const unsigned short* kbase = qbase + 512;
  const unsigned short* vb = vtg + (size_t)bh * 64 * 256;
  unsigned short* ob = obuf + (size_t)bb * 256 * 512 + hh * 64;

  for (int s = w; s < 16; s += 4) {
    const int q0 = s * 16;
    f32x4 sacc[16] = {};
    s16x8 aq[2];
    #pragma unroll
    for (int kk = 0; kk < 2; ++kk)
      aq[kk] = *(const s16x8*)(qbase + (size_t)(q0 + fr) * 1536 + kk * 32 + fg * 8);
    #pragma unroll
    for (int ni = 0; ni < 16; ++ni) {
      #pragma unroll
      for (int kk = 0; kk < 2; ++kk) {
        s16x8 bk = *(const s16x8*)(kbase + (size_t)(ni * 16 + fr) * 1536 + kk * 32 + fg * 8);
        sacc[ni] = __builtin_amdgcn_mfma_f32_16x16x32_bf16(aq[kk], bk, sacc[ni], 0, 0, 0);
      }
    }
    #pragma unroll
    for (int rr = 0; rr < 4; ++rr) {
      float mx = -1e30f;
      #pragma unroll
      for (int ni = 0; ni < 16; ++ni) mx = fmaxf(mx, sacc[ni][rr]);
      #pragma unroll
      for (int off = 1; off <= 8; off <<= 1) mx = fmaxf(mx, __shfl_xor(mx, off));
      float sum = 0.0f;
      #pragma unroll
      for (int ni = 0; ni < 16; ++ni) {
        float e = __expf((sacc[ni][rr] - mx) * 0.125f);
        sacc[ni][rr] = e; sum += e;
      }
      #pragma unroll
      for (int off = 1; off <= 8; off <<= 1) sum += __shfl_xor(sum, off);
      float inv = 1.0f / sum;
      #pragma unroll
      for (int ni = 0; ni < 16; ++ni) sacc[ni][rr] *= inv;
    }
    #pragma unroll
    for (int ni = 0; ni < 16; ++ni)
      #pragma unroll
      for (int rr = 0; rr < 4; ++rr)
        Pl[w][fg * 4 + rr][ni * 16 + fr] = f2b(sacc[ni][rr]);
    f32x4 oacc[4] = {};
    #pragma unroll
    for (int kk = 0; kk < 8; ++kk) {
      s16x8 ap = *(const s16x8*)&Pl[w][fr][kk * 32 + fg * 8];
      #pragma unroll
      for (int ni = 0; ni < 4; ++ni) {
        s16x8 bv = *(const s16x8*)(vb + (size_t)(ni * 16 + fr) * 256 + kk * 32 + fg * 8);
        oacc[ni] = __builtin_amdgcn_mfma_f32_16x16x32_bf16(ap, bv, oacc[ni], 0, 0, 0);
      }
    }
    #pragma unroll
    for (int ni = 0; ni < 4; ++ni)
      #pragma unroll
      for (int rr = 0; rr < 4; ++rr)
        ob[(size_t)(q0 + fg * 4 + rr) * 512 + ni * 16 + fr] = f2b(oacc[ni][rr]);
  }
}

extern "C" void kernel_launch(void* const* d_in, const int* in_sizes, int n_in,
                              void* d_out, int out_size, void* d_ws, size_t ws_size,
                              hipStream_t stream) {
  const int*   x      = (const int*)  d_in[0];
  const float* emb    = (const float*)d_in[1];
  const float* qkv_w  = (const float*)d_in[2];
  const float* qkv_b  = (const float*)d_in[3];
  const float* out_w  = (const float*)d_in[4];
  const float* out_b  = (const float*)d_in[5];
  const float* ln1_s  = (const float*)d_in[6];
  const float* ln1_b  = (const float*)d_in[7];
  const float* ln2_s  = (const float*)d_in[8];
  const float* ln2_b  = (const float*)d_in[9];
  const float* ff1_w  = (const float*)d_in[10];
  const float* ff1_b  = (const float*)d_in[11];
  const float* ff2_w  = (const float*)d_in[12];
  const float* ff2_b  = (const float*)d_in[13];
  const float* fn_s   = (const float*)d_in[14];
  const float* fn_b   = (const float*)d_in[15];
  const float* head_w = (const float*)d_in[16];
  float* out = (float*)d_out;

  char* p = (char*)d_ws;
  float* h = (float*)p;                      p += (size_t)NTOK * D_ * 4;
  unsigned short* x2b = (unsigned short*)p;  p += (size_t)NTOK * D_ * 2;
  unsigned short* qkvb = (unsigned short*)p; p += (size_t)NTOK * 3 * D_ * 2;
  unsigned short* vtg = (unsigned short*)p;  p += (size_t)B_ * H_ * DH_ * S_ * 2;
  unsigned short* obuf = (unsigned short*)p; p += (size_t)NTOK * D_ * 2;
  unsigned short* wt_qkv = (unsigned short*)p; p += (size_t)D_ * 3 * D_ * 2;
  unsigned short* wt_out = (unsigned short*)p; p += (size_t)D_ * D_ * 2;
  unsigned short* wt_ff1 = (unsigned short*)p; p += (size_t)D_ * FF_ * 2;
  unsigned short* wt_ff2 = (unsigned short*)p; p += (size_t)FF_ * D_ * 2;
  unsigned short* wth = (unsigned short*)p;    p += (size_t)NLOC_ * D_ * 2;
  unsigned short* ffmid = qkvb;  // alias: qkvb+vtg+obuf >= 64MB, dead during FF

  embed_kernel<<<NTOK, 256, 0, stream>>>(x, emb, h);
  wconv_kernel<<<dim3(NLOC_ / 64, D_ / 64), 256, 0, stream>>>(head_w, wth, D_, V_);

  for (int l = 0; l < L_; ++l) {
    wconv_kernel<<<dim3(3 * D_ / 64, D_ / 64), 256, 0, stream>>>(
        qkv_w + (size_t)l * D_ * 3 * D_, wt_qkv, D_, 3 * D_);
    wconv_kernel<<<dim3(D_ / 64, D_ / 64), 256, 0, stream>>>(
        out_w + (size_t)l * D_ * D_, wt_out, D_, D_);
    wconv_kernel<<<dim3(FF_ / 64, D_ / 64), 256, 0, stream>>>(
        ff1_w + (size_t)l * D_ * FF_, wt_ff1, D_, FF_);
    wconv_kernel<<<dim3(D_ / 64, FF_ / 64), 256, 0, stream>>>(
        ff2_w + (size_t)l * FF_ * D_, wt_ff2, FF_, D_);

    ln_kernel<<<NTOK, 256, 0, stream>>>(h, x2b, ln1_s + l * D_, ln1_b + l * D_);
    mfma_gemm<true, false, false, true><<<dim3(3 * D_ / 128, NTOK / 128), 256, 0, stream>>>(
        x2b, D_, wt_qkv, qkv_b + (size_t)l * 3 * D_, nullptr, qkvb,
        NTOK, 3 * D_, D_, 3 * D_);
    vt_kernel<<<dim3(B_ * H_, 4), 256, 0, stream>>>(qkvb, vtg);
    attn_mfma<<<B_ * H_, 256, 0, stream>>>(qkvb, vtg, obuf);
    mfma_gemm<true, false, true, false><<<dim3(D_ / 128, NTOK / 128), 256, 0, stream>>>(
        obuf, D_, wt_out, out_b + (size_t)l * D_, h, nullptr,
        NTOK, D_, D_, D_);
    ln_kernel<<<NTOK, 256, 0, stream>>>(h, x2b, ln2_s + l * D_, ln2_b + l * D_);
    mfma_gemm<true, true, false, true><<<dim3(FF_ / 128, NTOK / 128), 256, 0, stream>>>(
        x2b, D_, wt_ff1, ff1_b + (size_t)l * FF_, nullptr, ffmid,
        NTOK, FF_, D_, FF_);
    mfma_gemm<true, false, true, false><<<dim3(D_ / 128, NTOK / 128), 256, 0, stream>>>(
        ffmid, FF_, wt_ff2, ff2_b + (size_t)l * D_, h, nullptr,
        NTOK, D_, FF_, D_);
  }
  ln_kernel<<<NTOK, 256, 0, stream>>>(h, x2b, fn_s, fn_b);
  mfma_gemm<false, false, false, false><<<dim3(NLOC_ / 128, 1), 256, 0, stream>>>(
      x2b + (size_t)(S_ - 1) * D_, (long)S_ * D_, wth, nullptr, out, nullptr,
      B_, NLOC_, D_, NLOC_);
}